// Round 8
// baseline (2127.867 us; speedup 1.0000x reference)
//
#include <hip/hip_runtime.h>
#include <hip/hip_bf16.h>
#include <math.h>

#define H 128

typedef __bf16 bf16x8 __attribute__((ext_vector_type(8)));
typedef float f32x4 __attribute__((ext_vector_type(4)));
typedef __hip_bfloat16 bf16;

__device__ __forceinline__ bf16x8 ldb8(const bf16* p) {
  return *(const bf16x8*)(const void*)p;
}
__device__ __forceinline__ float fsig(float x) {
  return __fdividef(1.f, 1.f + __expf(-x));
}
__device__ __forceinline__ float ftanh(float x) {
  float x2 = fminf(fmaxf(2.f * x, -80.f), 80.f);
  float t = __expf(x2);
  return __fdividef(t - 1.f, t + 1.f);
}

// fused setup: [0,nb1) init_h ; [nb1,nb1+nb2) cvt whh ; [nb1+nb2,...) G
__global__ __launch_bounds__(256) void k_setup(const float* __restrict__ x,
                                               bf16* __restrict__ hb,
                                               const float* __restrict__ whh,
                                               bf16* __restrict__ whhb,
                                               const float* __restrict__ W,
                                               const float* __restrict__ wih,
                                               bf16* __restrict__ G,
                                               int N, int nb1, int nb2) {
  int b = blockIdx.x;
  if (b < nb1) {
    int i = b * 256 + threadIdx.x;
    if (i < N * H) {
      int f = i & (H - 1);
      int n = i >> 7;
      hb[i] = __float2bfloat16((f < 64) ? x[n * 64 + f] : 0.f);
    }
    return;
  }
  b -= nb1;
  if (b < nb2) {
    int i = b * 256 + threadIdx.x;
    if (i < 3 * H * H) whhb[i] = __float2bfloat16(whh[i]);
    return;
  }
  b -= nb2;
  int idx = b * 256 + threadIdx.x;
  if (idx >= 3 * 3 * H * H) return;
  int l = idx / (3 * H * H);
  int r = idx % (3 * H * H);
  int j = r >> 7;
  int k = r & (H - 1);
  const float4* a = (const float4*)(wih + (size_t)j * H);
  const float4* bb = (const float4*)(W + (size_t)l * H * H + (size_t)k * H);
  float s = 0.f;
#pragma unroll
  for (int q = 0; q < 32; q++) {
    float4 av = a[q], bv = bb[q];
    s += av.x * bv.x + av.y * bv.y + av.z * bv.z + av.w * bv.w;
  }
  G[idx] = __float2bfloat16(s);
}

// ---------- CSR build ----------
__global__ __launch_bounds__(256) void k_count(const int* __restrict__ dst,
                                               int* __restrict__ deg, int E) {
  int e = blockIdx.x * 256 + threadIdx.x;
  if (e < E) atomicAdd(&deg[dst[e]], 1);
}

__global__ __launch_bounds__(256) void k_bsum(const int* __restrict__ deg,
                                              int* __restrict__ bsums, int N) {
  __shared__ int ws[4];
  int t = threadIdx.x;
  int i = blockIdx.x * 256 + t;
  int v = (i < N) ? deg[i] : 0;
#pragma unroll
  for (int d = 1; d < 64; d <<= 1) v += __shfl_xor(v, d, 64);
  if ((t & 63) == 0) ws[t >> 6] = v;
  __syncthreads();
  if (t == 0) bsums[blockIdx.x] = ws[0] + ws[1] + ws[2] + ws[3];
}

__global__ __launch_bounds__(256) void k_bscan(int* __restrict__ bsums, int nb) {
  __shared__ int ws[4];
  int t = threadIdx.x;
  int lane = t & 63, w = t >> 6;
  int v = (t < nb) ? bsums[t] : 0;
  int s = v;
#pragma unroll
  for (int d = 1; d < 64; d <<= 1) {
    int u = __shfl_up(s, d, 64);
    if (lane >= d) s += u;
  }
  if (lane == 63) ws[w] = s;
  __syncthreads();
  int woff = 0;
  if (w >= 1) woff += ws[0];
  if (w >= 2) woff += ws[1];
  if (w >= 3) woff += ws[2];
  if (t < nb) bsums[t] = woff + s - v;
}

__global__ __launch_bounds__(256) void k_scan2(const int* __restrict__ deg,
                                               const int* __restrict__ bsums,
                                               int* __restrict__ rowptr,
                                               int* __restrict__ cursor,
                                               int N, int E) {
  __shared__ int ws[4];
  int t = threadIdx.x;
  int lane = t & 63, w = t >> 6;
  int i = blockIdx.x * 256 + t;
  int v = (i < N) ? deg[i] : 0;
  int s = v;
#pragma unroll
  for (int d = 1; d < 64; d <<= 1) {
    int u = __shfl_up(s, d, 64);
    if (lane >= d) s += u;
  }
  if (lane == 63) ws[w] = s;
  __syncthreads();
  int woff = 0;
  if (w >= 1) woff += ws[0];
  if (w >= 2) woff += ws[1];
  if (w >= 3) woff += ws[2];
  int excl = bsums[blockIdx.x] + woff + s - v;
  if (i < N) { rowptr[i] = excl; cursor[i] = excl; }
  if (i == 0) rowptr[N] = E;
}

// csr_pk[pos] = (src << 5) | (dst & 31)   (block row-ranges are 32-aligned)
__global__ __launch_bounds__(256) void k_fill(const int* __restrict__ src,
                                              const int* __restrict__ dst,
                                              int* __restrict__ cursor,
                                              int* __restrict__ csr_pk, int E) {
  int e = blockIdx.x * 256 + threadIdx.x;
  if (e < E) {
    int d = dst[e];
    int pos = atomicAdd(&cursor[d], 1);
    csr_pk[pos] = (src[e] << 5) | (d & 31);
  }
}

// bitonic sort of each 32-row block's edge segment by packed key (src-major)
__global__ __launch_bounds__(512) void k_sortseg(const int* __restrict__ rowptr,
                                                 int* __restrict__ csr_pk,
                                                 int N) {
  __shared__ int S[1024];
  int b = blockIdx.x;
  int r0 = b * 32;
  int r1 = r0 + 32; if (r1 > N) r1 = N;
  int seg0 = rowptr[r0], seg1 = rowptr[r1];
  int len = seg1 - seg0; if (len > 1024) len = 1024;  // tail unsorted: perf-only
  int t = threadIdx.x;
  for (int i = t; i < 1024; i += 512)
    S[i] = (i < len) ? csr_pk[seg0 + i] : 0x7FFFFFFF;
  __syncthreads();
  for (int k = 2; k <= 1024; k <<= 1) {
    for (int j = k >> 1; j > 0; j >>= 1) {
      int jm = j - 1;
      int i = ((t & ~jm) << 1) | (t & jm);
      int p = i | j;
      int a = S[i], c = S[p];
      bool up = ((i & k) == 0);
      if ((a > c) == up) { S[i] = c; S[p] = a; }
      __syncthreads();
    }
  }
  for (int i = t; i < len; i += 512) csr_pk[seg0 + i] = S[i];
}

// ---------- fused layer ----------
// block = 512 threads = 8 waves, owns 32 rows and their contiguous (sorted)
// edge segment. Gather: lane=(eslot=t&63), wave w = colgroup (16 cols);
// one instr fetches 64 distinct h-rows (sorted -> clustered addresses);
// accumulate fp32 LDS via ds_add. GRU: MFMA from LDS (A fp32->bf16 in regs).
#define HSTRIDE 136   // bf16 pad
#define AF 140        // float stride: 140*4B, mod-32-bank stride 12 -> 2-way max
__global__ __launch_bounds__(512) void k_layer(const bf16* __restrict__ hbin,
                                               bf16* __restrict__ hbout,
                                               const bf16* __restrict__ Gl,
                                               const bf16* __restrict__ whhb,
                                               const float* __restrict__ bih,
                                               const float* __restrict__ bhh,
                                               const int* __restrict__ rowptr,
                                               const int* __restrict__ csr_pk,
                                               int N) {
  __shared__ __align__(16) float Asf[32 * AF];
  __shared__ bf16 Hs[32 * HSTRIDE];
  int t = threadIdx.x;
  int w = t >> 6;
  int lane = t & 63;
  int row0 = blockIdx.x * 32;

  // ---- stage own h rows (coalesced) + zero Asf ----
  {
    int rl = t >> 4;
    int c = t & 15;
    int row = row0 + rl; if (row > N - 1) row = N - 1;
    bf16x8 v = ldb8(hbin + (size_t)row * H + c * 8);
    *(bf16x8*)(&Hs[rl * HSTRIDE + c * 8]) = v;
  }
  for (int i = t; i < 32 * AF; i += 512) Asf[i] = 0.f;
  __syncthreads();

  // ---- gather: flat sorted edge list, one edge per lane ----
  {
    int r1 = row0 + 32; if (r1 > N) r1 = N;
    int seg0 = rowptr[row0], seg1 = rowptr[r1];
    int co = w * 16;                       // this wave's 16-col chunk
    int i = seg0 + lane;
    // 2-way unrolled
    for (; i + 64 < seg1; i += 128) {
      int pk0 = csr_pk[i];
      int pk1 = csr_pk[i + 64];
      const bf16* p0 = hbin + ((size_t)(pk0 >> 5)) * H + co;
      const bf16* p1 = hbin + ((size_t)(pk1 >> 5)) * H + co;
      bf16x8 v0a = ldb8(p0), v0b = ldb8(p0 + 8);
      bf16x8 v1a = ldb8(p1), v1b = ldb8(p1 + 8);
      float* d0 = &Asf[(pk0 & 31) * AF + co];
      float* d1 = &Asf[(pk1 & 31) * AF + co];
#pragma unroll
      for (int j = 0; j < 8; j++) {
        atomicAdd(d0 + j,     (float)v0a[j]);
        atomicAdd(d0 + 8 + j, (float)v0b[j]);
      }
#pragma unroll
      for (int j = 0; j < 8; j++) {
        atomicAdd(d1 + j,     (float)v1a[j]);
        atomicAdd(d1 + 8 + j, (float)v1b[j]);
      }
    }
    if (i < seg1) {
      int pk0 = csr_pk[i];
      const bf16* p0 = hbin + ((size_t)(pk0 >> 5)) * H + co;
      bf16x8 v0a = ldb8(p0), v0b = ldb8(p0 + 8);
      float* d0 = &Asf[(pk0 & 31) * AF + co];
#pragma unroll
      for (int j = 0; j < 8; j++) {
        atomicAdd(d0 + j,     (float)v0a[j]);
        atomicAdd(d0 + 8 + j, (float)v0b[j]);
      }
    }
  }
  __syncthreads();

  // ---- GRU phase ----
  int r = lane & 15, quad = lane >> 4, laneK = quad * 8;
  int col = w * 16 + r;

  f32x4 aIR[2], aIZ[2], aIN[2], aHR[2], aHZ[2], aHN[2];
#pragma unroll
  for (int q = 0; q < 2; q++) {
    aIR[q] = (f32x4){0.f, 0.f, 0.f, 0.f};
    aIZ[q] = aIR[q]; aIN[q] = aIR[q];
    aHR[q] = aIR[q]; aHZ[q] = aIR[q]; aHN[q] = aIR[q];
  }

  size_t wo0 = (size_t)(0 * H + col) * H;
  size_t wo1 = (size_t)(1 * H + col) * H;
  size_t wo2 = (size_t)(2 * H + col) * H;

#pragma unroll
  for (int kb = 0; kb < 4; kb++) {
    int ko = kb * 32 + laneK;
    // A fragments: fp32 LDS -> bf16
    const float* ap0 = &Asf[r * AF + ko];
    const float* ap1 = &Asf[(16 + r) * AF + ko];
    f32x4 x0 = *(const f32x4*)ap0, x1 = *(const f32x4*)(ap0 + 4);
    f32x4 y0 = *(const f32x4*)ap1, y1 = *(const f32x4*)(ap1 + 4);
    bf16x8 a0, a1;
#pragma unroll
    for (int j = 0; j < 4; j++) {
      a0[j] = (__bf16)x0[j]; a0[j + 4] = (__bf16)x1[j];
      a1[j] = (__bf16)y0[j]; a1[j + 4] = (__bf16)y1[j];
    }
    bf16x8 h0 = *(const bf16x8*)(&Hs[r * HSTRIDE + ko]);
    bf16x8 h1 = *(const bf16x8*)(&Hs[(16 + r) * HSTRIDE + ko]);
    bf16x8 gr = ldb8(Gl + wo0 + ko);
    aIR[0] = __builtin_amdgcn_mfma_f32_16x16x32_bf16(a0, gr, aIR[0], 0, 0, 0);
    aIR[1] = __builtin_amdgcn_mfma_f32_16x16x32_bf16(a1, gr, aIR[1], 0, 0, 0);
    bf16x8 gz = ldb8(Gl + wo1 + ko);
    aIZ[0] = __builtin_amdgcn_mfma_f32_16x16x32_bf16(a0, gz, aIZ[0], 0, 0, 0);
    aIZ[1] = __builtin_amdgcn_mfma_f32_16x16x32_bf16(a1, gz, aIZ[1], 0, 0, 0);
    bf16x8 gn = ldb8(Gl + wo2 + ko);
    aIN[0] = __builtin_amdgcn_mfma_f32_16x16x32_bf16(a0, gn, aIN[0], 0, 0, 0);
    aIN[1] = __builtin_amdgcn_mfma_f32_16x16x32_bf16(a1, gn, aIN[1], 0, 0, 0);
    bf16x8 ur = ldb8(whhb + wo0 + ko);
    aHR[0] = __builtin_amdgcn_mfma_f32_16x16x32_bf16(h0, ur, aHR[0], 0, 0, 0);
    aHR[1] = __builtin_amdgcn_mfma_f32_16x16x32_bf16(h1, ur, aHR[1], 0, 0, 0);
    bf16x8 uz = ldb8(whhb + wo1 + ko);
    aHZ[0] = __builtin_amdgcn_mfma_f32_16x16x32_bf16(h0, uz, aHZ[0], 0, 0, 0);
    aHZ[1] = __builtin_amdgcn_mfma_f32_16x16x32_bf16(h1, uz, aHZ[1], 0, 0, 0);
    bf16x8 un = ldb8(whhb + wo2 + ko);
    aHN[0] = __builtin_amdgcn_mfma_f32_16x16x32_bf16(h0, un, aHN[0], 0, 0, 0);
    aHN[1] = __builtin_amdgcn_mfma_f32_16x16x32_bf16(h1, un, aHN[1], 0, 0, 0);
  }

  float bir = bih[col], biz = bih[H + col], bin = bih[2 * H + col];
  float bhr = bhh[col], bhz = bhh[H + col], bhn = bhh[2 * H + col];
#pragma unroll
  for (int q = 0; q < 2; q++) {
#pragma unroll
    for (int i = 0; i < 4; i++) {
      int lrow = q * 16 + quad * 4 + i;
      int row = row0 + lrow;
      if (row < N) {
        float rg = fsig(aIR[q][i] + bir + aHR[q][i] + bhr);
        float zg = fsig(aIZ[q][i] + biz + aHZ[q][i] + bhz);
        float ng = ftanh(aIN[q][i] + bin + rg * (aHN[q][i] + bhn));
        float hold = __bfloat162float(Hs[lrow * HSTRIDE + col]);
        float hp = (1.f - zg) * ng + zg * hold;
        hbout[(size_t)row * H + col] = __float2bfloat16(hp);
      }
    }
  }
}

// out[n,:] = log_softmax(h[n,:] @ lin_w^T + lin_b); one wave per node (bf16 h)
__global__ __launch_bounds__(256) void k_classify(const bf16* __restrict__ h,
                                                  const float* __restrict__ lw,
                                                  const float* __restrict__ lb,
                                                  float* __restrict__ out, int N) {
  int wave = (blockIdx.x * 256 + threadIdx.x) >> 6;
  int lane = threadIdx.x & 63;
  if (wave >= N) return;
  int c = lane & 15;
  int q = lane >> 4;
  const bf16* hr = h + (size_t)wave * H + q * 32;
  const float* wr = lw + c * H + q * 32;
  float p = 0.f;
#pragma unroll
  for (int k = 0; k < 32; k += 8) {
    bf16x8 a = ldb8(hr + k);
    float4 w0 = *(const float4*)(wr + k);
    float4 w1 = *(const float4*)(wr + k + 4);
    p += (float)a[0] * w0.x + (float)a[1] * w0.y + (float)a[2] * w0.z + (float)a[3] * w0.w;
    p += (float)a[4] * w1.x + (float)a[5] * w1.y + (float)a[6] * w1.z + (float)a[7] * w1.w;
  }
  p += __shfl_xor(p, 16, 64);
  p += __shfl_xor(p, 32, 64);
  float z = p + lb[c];
  float mx = z;
#pragma unroll
  for (int d = 1; d < 16; d <<= 1) mx = fmaxf(mx, __shfl_xor(mx, d, 64));
  float e = expf(z - mx);
  float s = e;
#pragma unroll
  for (int d = 1; d < 16; d <<= 1) s += __shfl_xor(s, d, 64);
  if (q == 0) out[(size_t)wave * 16 + c] = z - mx - logf(s);
}

extern "C" void kernel_launch(void* const* d_in, const int* in_sizes, int n_in,
                              void* d_out, int out_size, void* d_ws, size_t ws_size,
                              hipStream_t stream) {
  const float* x   = (const float*)d_in[0];
  const int*   ei  = (const int*)d_in[1];
  const float* W   = (const float*)d_in[2];
  const float* wih = (const float*)d_in[3];
  const float* whh = (const float*)d_in[4];
  const float* bih = (const float*)d_in[5];
  const float* bhh = (const float*)d_in[6];
  const float* lw  = (const float*)d_in[7];
  const float* lb  = (const float*)d_in[8];
  float* out = (float*)d_out;

  int N = in_sizes[0] / 64;   // 50000
  int E = in_sizes[1] / 2;    // 800000
  const int* src = ei;
  const int* dst = ei + E;

  size_t NH = (size_t)N * H;
  bf16* hb0  = (bf16*)d_ws;                  // [N,H] bf16 h ping
  bf16* hb1  = hb0 + NH;                     // [N,H] bf16 h pong
  bf16* Gb   = hb1 + NH;                     // [3][3H,H]
  bf16* whhb = Gb + 3 * 3 * H * H;           // [3H,H]
  int* deg     = (int*)(whhb + 3 * H * H);
  int* rowptr  = deg + N;                    // N+1
  int* cursor  = rowptr + N + 1;             // N
  int* bsums   = cursor + N;                 // <=256
  int* csr_pk  = bsums + 256;                // E

  int nb_e  = (E + 255) / 256;
  int nb_n  = (N + 255) / 256;

  int nb1 = (int)((NH + 255) / 256);
  int nb2 = (3 * H * H + 255) / 256;
  int nb3 = (3 * 3 * H * H + 255) / 256;
  k_setup<<<nb1 + nb2 + nb3, 256, 0, stream>>>(x, hb0, whh, whhb, W, wih, Gb,
                                               N, nb1, nb2);

  hipMemsetAsync(deg, 0, (size_t)N * sizeof(int), stream);
  k_count<<<nb_e, 256, 0, stream>>>(dst, deg, E);
  k_bsum<<<nb_n, 256, 0, stream>>>(deg, bsums, N);
  k_bscan<<<1, 256, 0, stream>>>(bsums, nb_n);
  k_scan2<<<nb_n, 256, 0, stream>>>(deg, bsums, rowptr, cursor, N, E);
  k_fill<<<nb_e, 256, 0, stream>>>(src, dst, cursor, csr_pk, E);

  int nb_layer = (N + 31) / 32;
  k_sortseg<<<nb_layer, 512, 0, stream>>>(rowptr, csr_pk, N);

  bf16* hbp[2] = {hb0, hb1};
  for (int l = 0; l < 3; l++) {
    bf16* hin  = hbp[l & 1];
    bf16* hout = hbp[(l + 1) & 1];
    k_layer<<<nb_layer, 512, 0, stream>>>(hin, hout,
                                          Gb + (size_t)l * 3 * H * H, whhb,
                                          bih, bhh, rowptr, csr_pk, N);
  }

  k_classify<<<(N + 3) / 4, 256, 0, stream>>>(hb1, lw, lb, out, N);
}

// Round 9
// 576.158 us; speedup vs baseline: 3.6932x; 3.6932x over previous
//
#include <hip/hip_runtime.h>
#include <hip/hip_bf16.h>
#include <math.h>

#define H 128

typedef __bf16 bf16x8 __attribute__((ext_vector_type(8)));
typedef float f32x4 __attribute__((ext_vector_type(4)));
typedef __hip_bfloat16 bf16;

__device__ __forceinline__ bf16x8 ldb8(const bf16* p) {
  return *(const bf16x8*)(const void*)p;
}
__device__ __forceinline__ float fsig(float x) {
  return __fdividef(1.f, 1.f + __expf(-x));
}
__device__ __forceinline__ float ftanh(float x) {
  float x2 = fminf(fmaxf(2.f * x, -80.f), 80.f);
  float t = __expf(x2);
  return __fdividef(t - 1.f, t + 1.f);
}

// grid barrier: G co-resident blocks, monotone epoch counter (memset to 0/launch)
__device__ __forceinline__ void gridbar(int* ctr, int target) {
  __syncthreads();
  if (threadIdx.x == 0) {
    __threadfence();
    atomicAdd(ctr, 1);
    while (atomicAdd(ctr, 0) < target) __builtin_amdgcn_s_sleep(2);
    __threadfence();
  }
  __syncthreads();
}

// ---------- fused setup + CSR build (G = ceil(N/256) blocks, co-resident) ----
__global__ __launch_bounds__(256) void k_csr(const float* __restrict__ x,
                                             const float* __restrict__ whh,
                                             const float* __restrict__ W,
                                             const float* __restrict__ wih,
                                             bf16* __restrict__ hb,
                                             bf16* __restrict__ whhb,
                                             bf16* __restrict__ Gm,
                                             const int* __restrict__ src,
                                             const int* __restrict__ dst,
                                             int* __restrict__ deg,
                                             int* __restrict__ rowptr,
                                             int* __restrict__ cursor,
                                             int* __restrict__ bsums,
                                             int* __restrict__ csr_src,
                                             int* __restrict__ bar,
                                             int N, int E, int G) {
  __shared__ int ws[4];
  int t = threadIdx.x, b = blockIdx.x;
  int gid = b * 256 + t;
  int nth = G * 256;

  // pre-phase: zero deg + init h + cvt whh + compute Gm
  for (int i = gid; i < N; i += nth) deg[i] = 0;
  for (int i = gid; i < N * H; i += nth) {
    int f = i & (H - 1);
    int n = i >> 7;
    hb[i] = __float2bfloat16((f < 64) ? x[n * 64 + f] : 0.f);
  }
  for (int i = gid; i < 3 * H * H; i += nth)
    whhb[i] = __float2bfloat16(whh[i]);
  for (int idx = gid; idx < 3 * 3 * H * H; idx += nth) {
    int l = idx / (3 * H * H);
    int r = idx % (3 * H * H);
    int j = r >> 7;
    int k = r & (H - 1);
    const float4* a = (const float4*)(wih + (size_t)j * H);
    const float4* bb = (const float4*)(W + (size_t)l * H * H + (size_t)k * H);
    float s = 0.f;
#pragma unroll
    for (int q = 0; q < 32; q++) {
      float4 av = a[q], bv = bb[q];
      s += av.x * bv.x + av.y * bv.y + av.z * bv.z + av.w * bv.w;
    }
    Gm[idx] = __float2bfloat16(s);
  }
  gridbar(bar, G * 1);

  // count
  for (int i = gid; i < E; i += nth) atomicAdd(&deg[dst[i]], 1);
  gridbar(bar, G * 2);

  // per-chunk sums (chunk b)
  {
    int i = b * 256 + t;
    int v = (i < N) ? deg[i] : 0;
    int sv = v;
#pragma unroll
    for (int d = 1; d < 64; d <<= 1) sv += __shfl_xor(sv, d, 64);
    if ((t & 63) == 0) ws[t >> 6] = sv;
    __syncthreads();
    if (t == 0) bsums[b] = ws[0] + ws[1] + ws[2] + ws[3];
  }
  gridbar(bar, G * 3);

  // block 0: exclusive scan of bsums (G <= 256)
  if (b == 0) {
    int lane = t & 63, w2 = t >> 6;
    int v = (t < G) ? bsums[t] : 0;
    int s = v;
#pragma unroll
    for (int d = 1; d < 64; d <<= 1) {
      int u = __shfl_up(s, d, 64);
      if (lane >= d) s += u;
    }
    if (lane == 63) ws[w2] = s;
    __syncthreads();
    int woff = 0;
    if (w2 >= 1) woff += ws[0];
    if (w2 >= 2) woff += ws[1];
    if (w2 >= 3) woff += ws[2];
    if (t < G) bsums[t] = woff + s - v;
  }
  gridbar(bar, G * 4);

  // local rescan + offset -> rowptr, cursor (chunk b)
  {
    int lane = t & 63, w2 = t >> 6;
    int i = b * 256 + t;
    int v = (i < N) ? deg[i] : 0;
    int s = v;
#pragma unroll
    for (int d = 1; d < 64; d <<= 1) {
      int u = __shfl_up(s, d, 64);
      if (lane >= d) s += u;
    }
    if (lane == 63) ws[w2] = s;
    __syncthreads();
    int woff = 0;
    if (w2 >= 1) woff += ws[0];
    if (w2 >= 2) woff += ws[1];
    if (w2 >= 3) woff += ws[2];
    int excl = bsums[b] + woff + s - v;
    if (i < N) { rowptr[i] = excl; cursor[i] = excl; }
    if (gid == 0) rowptr[N] = E;
  }
  gridbar(bar, G * 5);

  // fill
  for (int i = gid; i < E; i += nth) {
    int pos = atomicAdd(&cursor[dst[i]], 1);
    csr_src[pos] = src[i];
  }
}

// ---------- fused layer: gather -> GRU (-> classify on last layer) ----------
// block = 512 threads = 8 waves, owns 32 rows.
#define HSTRIDE 136
#define FS 132
__global__ __launch_bounds__(512) void k_layer(const bf16* __restrict__ hbin,
                                               bf16* __restrict__ hbout,
                                               const bf16* __restrict__ Gl,
                                               const bf16* __restrict__ whhb,
                                               const float* __restrict__ bih,
                                               const float* __restrict__ bhh,
                                               const int* __restrict__ rowptr,
                                               const int* __restrict__ csr_src,
                                               const float* __restrict__ lw,
                                               const float* __restrict__ lb,
                                               float* __restrict__ out,
                                               int do_cls, int N) {
  __shared__ __align__(16) char smem[32 * HSTRIDE * 2 * 2];
  bf16* As = (bf16*)smem;                      // 32*136 bf16
  bf16* Hs = (bf16*)(smem + 32 * HSTRIDE * 2); // 32*136 bf16
  float* F = (float*)smem;                     // 32*132 fp32 (classify alias)
  int t = threadIdx.x;
  int w = t >> 6;
  int lane = t & 63;
  int row0 = blockIdx.x * 32;

  // ---- stage own h rows (coalesced) ----
  {
    int rl = t >> 4;
    int c = t & 15;
    int row = row0 + rl; if (row > N - 1) row = N - 1;
    bf16x8 v = ldb8(hbin + (size_t)row * H + c * 8);
    *(bf16x8*)(&Hs[rl * HSTRIDE + c * 8]) = v;
  }

  // ---- gather: 8 slots x 8 colgroups, 2-way unrolled (R7 structure) ----
  {
    int s = lane >> 3;
    int c = lane & 7;
    int co = c * 16;
    for (int rr = 0; rr < 4; rr++) {
      int rl = w * 4 + rr;
      int row = row0 + rl;
      float acc[16];
#pragma unroll
      for (int j = 0; j < 16; j++) acc[j] = 0.f;
      if (row < N) {
        int b = rowptr[row], e = rowptr[row + 1];
        int i = b + s;
        for (; i + 8 < e; i += 16) {
          int s0 = csr_src[i];
          int s1 = csr_src[i + 8];
          const bf16* p0 = hbin + (size_t)s0 * H + co;
          const bf16* p1 = hbin + (size_t)s1 * H + co;
          bf16x8 v0a = ldb8(p0), v0b = ldb8(p0 + 8);
          bf16x8 v1a = ldb8(p1), v1b = ldb8(p1 + 8);
#pragma unroll
          for (int j = 0; j < 8; j++) {
            acc[j]     += (float)v0a[j] + (float)v1a[j];
            acc[j + 8] += (float)v0b[j] + (float)v1b[j];
          }
        }
        if (i < e) {
          int s0 = csr_src[i];
          const bf16* p0 = hbin + (size_t)s0 * H + co;
          bf16x8 v0a = ldb8(p0), v0b = ldb8(p0 + 8);
#pragma unroll
          for (int j = 0; j < 8; j++) {
            acc[j]     += (float)v0a[j];
            acc[j + 8] += (float)v0b[j];
          }
        }
      }
#pragma unroll
      for (int j = 0; j < 16; j++) {
        acc[j] += __shfl_xor(acc[j], 8, 64);
        acc[j] += __shfl_xor(acc[j], 16, 64);
        acc[j] += __shfl_xor(acc[j], 32, 64);
      }
      if (s == 0) {
        bf16x8 oa, ob;
#pragma unroll
        for (int j = 0; j < 8; j++) { oa[j] = (__bf16)acc[j]; ob[j] = (__bf16)acc[j + 8]; }
        *(bf16x8*)(&As[rl * HSTRIDE + co]) = oa;
        *(bf16x8*)(&As[rl * HSTRIDE + co + 8]) = ob;
      }
    }
  }
  __syncthreads();

  // ---- GRU phase ----
  int r = lane & 15, quad = lane >> 4, laneK = quad * 8;
  int col = w * 16 + r;

  f32x4 aIR[2], aIZ[2], aIN[2], aHR[2], aHZ[2], aHN[2];
#pragma unroll
  for (int q = 0; q < 2; q++) {
    aIR[q] = (f32x4){0.f, 0.f, 0.f, 0.f};
    aIZ[q] = aIR[q]; aIN[q] = aIR[q];
    aHR[q] = aIR[q]; aHZ[q] = aIR[q]; aHN[q] = aIR[q];
  }

  size_t wo0 = (size_t)(0 * H + col) * H;
  size_t wo1 = (size_t)(1 * H + col) * H;
  size_t wo2 = (size_t)(2 * H + col) * H;

#pragma unroll
  for (int kb = 0; kb < 4; kb++) {
    int ko = kb * 32 + laneK;
    bf16x8 a0 = *(const bf16x8*)(&As[r * HSTRIDE + ko]);
    bf16x8 a1 = *(const bf16x8*)(&As[(16 + r) * HSTRIDE + ko]);
    bf16x8 h0 = *(const bf16x8*)(&Hs[r * HSTRIDE + ko]);
    bf16x8 h1 = *(const bf16x8*)(&Hs[(16 + r) * HSTRIDE + ko]);
    bf16x8 gr = ldb8(Gl + wo0 + ko);
    aIR[0] = __builtin_amdgcn_mfma_f32_16x16x32_bf16(a0, gr, aIR[0], 0, 0, 0);
    aIR[1] = __builtin_amdgcn_mfma_f32_16x16x32_bf16(a1, gr, aIR[1], 0, 0, 0);
    bf16x8 gz = ldb8(Gl + wo1 + ko);
    aIZ[0] = __builtin_amdgcn_mfma_f32_16x16x32_bf16(a0, gz, aIZ[0], 0, 0, 0);
    aIZ[1] = __builtin_amdgcn_mfma_f32_16x16x32_bf16(a1, gz, aIZ[1], 0, 0, 0);
    bf16x8 gn = ldb8(Gl + wo2 + ko);
    aIN[0] = __builtin_amdgcn_mfma_f32_16x16x32_bf16(a0, gn, aIN[0], 0, 0, 0);
    aIN[1] = __builtin_amdgcn_mfma_f32_16x16x32_bf16(a1, gn, aIN[1], 0, 0, 0);
    bf16x8 ur = ldb8(whhb + wo0 + ko);
    aHR[0] = __builtin_amdgcn_mfma_f32_16x16x32_bf16(h0, ur, aHR[0], 0, 0, 0);
    aHR[1] = __builtin_amdgcn_mfma_f32_16x16x32_bf16(h1, ur, aHR[1], 0, 0, 0);
    bf16x8 uz = ldb8(whhb + wo1 + ko);
    aHZ[0] = __builtin_amdgcn_mfma_f32_16x16x32_bf16(h0, uz, aHZ[0], 0, 0, 0);
    aHZ[1] = __builtin_amdgcn_mfma_f32_16x16x32_bf16(h1, uz, aHZ[1], 0, 0, 0);
    bf16x8 un = ldb8(whhb + wo2 + ko);
    aHN[0] = __builtin_amdgcn_mfma_f32_16x16x32_bf16(h0, un, aHN[0], 0, 0, 0);
    aHN[1] = __builtin_amdgcn_mfma_f32_16x16x32_bf16(h1, un, aHN[1], 0, 0, 0);
  }

  float bir = bih[col], biz = bih[H + col], bin = bih[2 * H + col];
  float bhr = bhh[col], bhz = bhh[H + col], bhn = bhh[2 * H + col];
  float hp[2][4];
#pragma unroll
  for (int q = 0; q < 2; q++) {
#pragma unroll
    for (int i = 0; i < 4; i++) {
      int lrow = q * 16 + quad * 4 + i;
      float rg = fsig(aIR[q][i] + bir + aHR[q][i] + bhr);
      float zg = fsig(aIZ[q][i] + biz + aHZ[q][i] + bhz);
      float ng = ftanh(aIN[q][i] + bin + rg * (aHN[q][i] + bhn));
      float hold = __bfloat162float(Hs[lrow * HSTRIDE + col]);
      hp[q][i] = (1.f - zg) * ng + zg * hold;
    }
  }

  if (!do_cls) {
#pragma unroll
    for (int q = 0; q < 2; q++) {
#pragma unroll
      for (int i = 0; i < 4; i++) {
        int row = row0 + q * 16 + quad * 4 + i;
        if (row < N)
          hbout[(size_t)row * H + col] = __float2bfloat16(hp[q][i]);
      }
    }
    return;
  }

  // ---- fused classify (layer 3): h' -> LDS fp32, 1 thread per (row,class) ----
  __syncthreads();   // all As/Hs reads done before aliasing overwrite
#pragma unroll
  for (int q = 0; q < 2; q++) {
#pragma unroll
    for (int i = 0; i < 4; i++) {
      int lrow = q * 16 + quad * 4 + i;
      F[lrow * FS + col] = hp[q][i];
    }
  }
  __syncthreads();
  {
    int rl = t >> 4;        // local row 0..31
    int cls = t & 15;       // class
    int row = row0 + rl;
    if (row < N) {
      const float* hv = &F[rl * FS];
      const float* wv = lw + cls * H;
      float p = 0.f;
#pragma unroll
      for (int k = 0; k < H; k += 4) {
        float4 wq = *(const float4*)(wv + k);
        p += hv[k] * wq.x + hv[k + 1] * wq.y + hv[k + 2] * wq.z + hv[k + 3] * wq.w;
      }
      p += lb[cls];
      float mx = p;
#pragma unroll
      for (int d = 1; d < 16; d <<= 1) mx = fmaxf(mx, __shfl_xor(mx, d, 64));
      float e = expf(p - mx);
      float s = e;
#pragma unroll
      for (int d = 1; d < 16; d <<= 1) s += __shfl_xor(s, d, 64);
      out[(size_t)row * 16 + cls] = p - mx - logf(s);
    }
  }
}

extern "C" void kernel_launch(void* const* d_in, const int* in_sizes, int n_in,
                              void* d_out, int out_size, void* d_ws, size_t ws_size,
                              hipStream_t stream) {
  const float* x   = (const float*)d_in[0];
  const int*   ei  = (const int*)d_in[1];
  const float* W   = (const float*)d_in[2];
  const float* wih = (const float*)d_in[3];
  const float* whh = (const float*)d_in[4];
  const float* bih = (const float*)d_in[5];
  const float* bhh = (const float*)d_in[6];
  const float* lw  = (const float*)d_in[7];
  const float* lb  = (const float*)d_in[8];
  float* out = (float*)d_out;

  int N = in_sizes[0] / 64;   // 50000
  int E = in_sizes[1] / 2;    // 800000
  const int* src = ei;
  const int* dst = ei + E;

  size_t NH = (size_t)N * H;
  bf16* hb0  = (bf16*)d_ws;                  // [N,H] bf16 h ping
  bf16* hb1  = hb0 + NH;                     // [N,H] bf16 h pong
  bf16* Gb   = hb1 + NH;                     // [3][3H,H]
  bf16* whhb = Gb + 3 * 3 * H * H;           // [3H,H]
  int* deg     = (int*)(whhb + 3 * H * H);
  int* rowptr  = deg + N;                    // N+1
  int* cursor  = rowptr + N + 1;             // N
  int* bsums   = cursor + N;                 // <=256
  int* bar     = bsums + 256;                // 16
  int* csr_src = bar + 16;                   // E

  int G = (N + 255) / 256;                   // 196 co-resident blocks

  hipMemsetAsync(bar, 0, 64, stream);
  k_csr<<<G, 256, 0, stream>>>(x, whh, W, wih, hb0, whhb, Gb,
                               src, dst, deg, rowptr, cursor, bsums,
                               csr_src, bar, N, E, G);

  int nb_layer = (N + 31) / 32;
  bf16* hbp[2] = {hb0, hb1};
  for (int l = 0; l < 3; l++) {
    bf16* hin  = hbp[l & 1];
    bf16* hout = hbp[(l + 1) & 1];
    k_layer<<<nb_layer, 512, 0, stream>>>(hin, hout,
                                          Gb + (size_t)l * 3 * H * H, whhb,
                                          bih, bhh, rowptr, csr_src,
                                          lw, lb, out, (l == 2) ? 1 : 0, N);
  }
}